// Round 1
// 478.786 us; speedup vs baseline: 1.2604x; 1.2604x over previous
//
#include <hip/hip_runtime.h>
#include <stdint.h>

typedef unsigned short u16;
typedef __attribute__((ext_vector_type(8))) short short8;
typedef __attribute__((ext_vector_type(4))) float floatx4;

#define BB 16
#define NN1 1024
#define NN2 4096
#define DIM 512
#define M1 (BB*NN1)    // 16384
#define M2 (BB*NN2)    // 65536

__device__ __forceinline__ float bf2f(u16 u){
  union { unsigned int i; float f; } v; v.i = ((unsigned int)u) << 16; return v.f;
}
__device__ __forceinline__ u16 f2bf(float f){
  union { float f; unsigned int i; } v; v.f = f;
  unsigned int i = v.i;
  return (u16)((i + 0x7FFFu + ((i >> 16) & 1u)) >> 16);  // RNE (exact for bf16-quantized)
}

// ---------------- zero stats ----------------
__global__ void zero_stats(float* p){
  p[blockIdx.x * 256 + threadIdx.x] = 0.0f;   // grid 8 -> 2048 floats
}

// ---- weight transpose + f32->bf16: src f32 [K][N] -> dst bf16 [N][K] ----
__global__ void transpose_w(const float* __restrict__ src, u16* __restrict__ dst,
                            int K, int N){
  int idx = blockIdx.x * 256 + threadIdx.x;
  if (idx < K * N){
    int n = idx / K, k = idx % K;
    dst[idx] = f2bf(src[k * N + n]);
  }
}

// ---- MFMA GEMM: Y[M][512] = A_f32[M][K] @ W; BT = bf16 W^T [512][K] ----
// 1D grid, XCD-aware swizzle: the 4 bn-blocks sharing an A panel land on ONE XCD.
// Fused per-column sum/sumsq (BN stats) via block reduction + atomics.
__global__ __launch_bounds__(256) void gemm_mfma(
    const float* __restrict__ A, const u16* __restrict__ BT,
    const float* __restrict__ bias, void* __restrict__ Yv,
    int M, int K, int out_is_f32,
    float* __restrict__ sum, float* __restrict__ sumsq)
{
  const int N = 512;
  // unpadded [128][32] bf16, chunk pos = kc ^ ((row>>1)&3): conflict-free b128 r/w
  __shared__ u16 As[128 * 32];
  __shared__ u16 Bs[128 * 32];
  int tid  = threadIdx.x;
  int lane = tid & 63, wave = tid >> 6;

  // swizzle decode: id%8 == bm%8 -> same-panel blocks share an XCD L2
  int id = blockIdx.x;
  int bm = (id & 7) + ((id >> 5) << 3);
  int bn = (id >> 3) & 3;

  int wm = (wave & 1) * 64, wn = (wave >> 1) * 64;
  int r16 = lane & 15, quad = lane >> 4;

  floatx4 acc[4][4];
  for (int i = 0; i < 4; i++)
    for (int j = 0; j < 4; j++)
      acc[i][j] = (floatx4)(0.0f);

  int lr = tid >> 2;            // 0..63
  int kc = tid & 3;             // k-chunk 0..3 (8 consecutive k per thread)

  const float* Ag = A  + (size_t)(bm * 128) * K;
  const u16*   Bg = BT + (size_t)(bn * 128) * K;

  int rsw = ((r16 >> 1) & 3) ^ quad;   // read chunk position (XOR un-swizzle)

  for (int k0 = 0; k0 < K; k0 += 32){
    for (int rr = 0; rr < 2; rr++){
      int row = lr + rr * 64;
      const float* ap = Ag + (size_t)row * K + k0 + kc * 8;
      float4 a0 = *(const float4*)ap;
      float4 a1 = *(const float4*)(ap + 4);
      u16 t[8] = { f2bf(a0.x), f2bf(a0.y), f2bf(a0.z), f2bf(a0.w),
                   f2bf(a1.x), f2bf(a1.y), f2bf(a1.z), f2bf(a1.w) };
      int dst = row * 32 + ((kc ^ ((row >> 1) & 3)) * 8);
      *(uint4*)(&As[dst]) = *(const uint4*)t;
      uint4 vb = *(const uint4*)(Bg + (size_t)row * K + k0 + kc * 8);
      *(uint4*)(&Bs[dst]) = vb;
    }
    __syncthreads();
    short8 af[4], bfr[4];
    for (int i = 0; i < 4; i++) af[i]  = *(const short8*)(&As[(wm + i*16 + r16) * 32 + rsw * 8]);
    for (int j = 0; j < 4; j++) bfr[j] = *(const short8*)(&Bs[(wn + j*16 + r16) * 32 + rsw * 8]);
    for (int i = 0; i < 4; i++)
      for (int j = 0; j < 4; j++)
        acc[i][j] = __builtin_amdgcn_mfma_f32_16x16x32_bf16(af[i], bfr[j], acc[i][j], 0, 0, 0);
    __syncthreads();
  }

  // epilogue: C/D layout col = lane&15, row = quad*4 + reg (m89-verified)
  float cs[4] = {0.f, 0.f, 0.f, 0.f};
  float cq[4] = {0.f, 0.f, 0.f, 0.f};
  for (int i = 0; i < 4; i++){
    int rowb = bm * 128 + wm + i * 16 + quad * 4;
    for (int j = 0; j < 4; j++){
      int col = bn * 128 + wn + j * 16 + r16;
      float bv = bias[col];
      for (int r = 0; r < 4; r++){
        float v = acc[i][j][r] + bv;
        cs[j] += v; cq[j] += v * v;
        size_t idx = (size_t)(rowb + r) * N + col;
        if (out_is_f32) ((float*)Yv)[idx] = v;
        else            ((u16*)Yv)[idx]   = f2bf(v);
      }
    }
  }

  // column-stat reduction: quads within wave (shfl), wm-halves via LDS, 1 atomic each
  for (int j = 0; j < 4; j++){
    cs[j] += __shfl_xor(cs[j], 16); cs[j] += __shfl_xor(cs[j], 32);
    cq[j] += __shfl_xor(cq[j], 16); cq[j] += __shfl_xor(cq[j], 32);
  }
  float* S = (float*)As;   // reuse: [wmh][stat][128 cols] = 512 f32
  if (lane < 16){
    int wmh = wave & 1, wnh = wave >> 1;
    for (int j = 0; j < 4; j++){
      int c = wnh * 64 + j * 16 + r16;
      S[wmh * 256 + c]       = cs[j];
      S[wmh * 256 + 128 + c] = cq[j];
    }
  }
  __syncthreads();
  {
    int stat = tid >> 7, c = tid & 127;
    float v = S[stat * 128 + c] + S[256 + stat * 128 + c];
    float* dstp = stat ? sumsq : sum;
    atomicAdd(&dstp[bn * 128 + c], v);
  }
}

// ---------------- BN coefficients: a = gamma/sqrt(var+eps), b = beta - mu*a ----------------
__global__ void bn_coeff(const float* __restrict__ stats,
                         const float* __restrict__ g1, const float* __restrict__ be1,
                         const float* __restrict__ g2, const float* __restrict__ be2,
                         float* __restrict__ coef){
  int c = threadIdx.x;  // 512
  {
    float mu  = stats[c] / (float)M1;
    float var = stats[512 + c] / (float)M1 - mu * mu;
    var = fmaxf(var, 0.0f);
    float a = g1[c] * (1.0f / sqrtf(var + 1e-5f));
    coef[c] = a;
    coef[512 + c] = be1[c] - mu * a;
  }
  {
    float mu  = stats[1024 + c] / (float)M2;
    float var = stats[1536 + c] / (float)M2 - mu * mu;
    var = fmaxf(var, 0.0f);
    float a = g2[c] * (1.0f / sqrtf(var + 1e-5f));
    coef[1024 + c] = a;
    coef[1536 + c] = be2[c] - mu * a;
  }
}

// ---------------- xyz2 passthrough (bit-exact f32 copy: 786432 B) ----------------
__global__ void copy_xyz(const uint4* __restrict__ src, uint4* __restrict__ dst){
  int i = blockIdx.x * 256 + threadIdx.x;   // grid 192 -> 49152 * 16B
  dst[i] = src[i];
}

// ---- 3-NN inverse-distance interp FUSED with BN1/BN2+ReLU+add; one wave/query ----
// outF row holds pre-BN Y2 (f32) on entry; on exit it holds the final feats row.
__global__ __launch_bounds__(64) void interp_final(
    const float* __restrict__ xyz1, const float* __restrict__ xyz2,
    const u16* __restrict__ Y1, const float* __restrict__ coef,
    float* __restrict__ outF)
{
  int lane = threadIdx.x;
  int bid  = blockIdx.x;
  int b = bid >> 12;           // /4096

  const float* pd = xyz2 + (size_t)bid * 3;
  double xd = (double)pd[0];
  double yd = (double)pd[1];
  double zd = (double)pd[2];

  // f64 distances (exact for bf16-quantized coords -> true ordering)
  double dl[16];
  const float* ps = xyz1 + (size_t)b * NN1 * 3;
  for (int s = 0; s < 16; s++){
    const float* q = ps + (s * 64 + lane) * 3;
    double dx = xd - (double)q[0];
    double dy = yd - (double)q[1];
    double dz = zd - (double)q[2];
    dl[s] = dx * dx + dy * dy + dz * dz;
  }

  double dsel[3]; int isel[3];
  for (int p = 0; p < 3; p++){
    double dm = dl[0]; int sm = 0;
    for (int s = 1; s < 16; s++) if (dl[s] < dm){ dm = dl[s]; sm = s; }
    int im = sm * 64 + lane;
    for (int off = 1; off < 64; off <<= 1){
      double od = __shfl_xor(dm, off);
      int    oi = __shfl_xor(im, off);
      if (od < dm || (od == dm && oi < im)){ dm = od; im = oi; }  // stable: lowest index
    }
    dsel[p] = dm; isel[p] = im;
    if ((im & 63) == lane) dl[im >> 6] = 1e300;  // owner invalidates winner
  }

  double w0 = 1.0 / (dsel[0] + 1e-8);
  double w1 = 1.0 / (dsel[1] + 1e-8);
  double w2 = 1.0 / (dsel[2] + 1e-8);
  double wsum = w0 + w1 + w2;
  float f0 = (float)(w0 / wsum), f1 = (float)(w1 / wsum), f2 = (float)(w2 / wsum);

  const u16* r0 = Y1 + (size_t)(b * NN1 + isel[0]) * DIM;
  const u16* r1 = Y1 + (size_t)(b * NN1 + isel[1]) * DIM;
  const u16* r2 = Y1 + (size_t)(b * NN1 + isel[2]) * DIM;
  float* o = outF + (size_t)bid * DIM;

  int c0 = lane * 8;  // 8 contiguous channels per lane
  uint4 q0 = *(const uint4*)(r0 + c0);
  uint4 q1 = *(const uint4*)(r1 + c0);
  uint4 q2 = *(const uint4*)(r2 + c0);
  float4 ylo = *(const float4*)(o + c0);
  float4 yhi = *(const float4*)(o + c0 + 4);
  const u16* p0 = (const u16*)&q0;
  const u16* p1 = (const u16*)&q1;
  const u16* p2 = (const u16*)&q2;
  float yv[8] = { ylo.x, ylo.y, ylo.z, ylo.w, yhi.x, yhi.y, yhi.z, yhi.w };
  float res[8];
  for (int j = 0; j < 8; j++){
    int c = c0 + j;
    float a1 = coef[c],        b1 = coef[512 + c];
    float a2 = coef[1024 + c], b2 = coef[1536 + c];
    float v0 = fmaxf(a1 * bf2f(p0[j]) + b1, 0.0f);
    float v1 = fmaxf(a1 * bf2f(p1[j]) + b1, 0.0f);
    float v2 = fmaxf(a1 * bf2f(p2[j]) + b1, 0.0f);
    float vi = f0 * v0 + f1 * v1 + f2 * v2;
    float y2 = fmaxf(a2 * yv[j] + b2, 0.0f);
    res[j] = vi + y2;
  }
  *(float4*)(o + c0)     = make_float4(res[0], res[1], res[2], res[3]);
  *(float4*)(o + c0 + 4) = make_float4(res[4], res[5], res[6], res[7]);
}

extern "C" void kernel_launch(void* const* d_in, const int* in_sizes, int n_in,
                              void* d_out, int out_size, void* d_ws, size_t ws_size,
                              hipStream_t stream){
  const float* xyz1    = (const float*)d_in[0];
  const float* points1 = (const float*)d_in[1];
  const float* xyz2    = (const float*)d_in[2];
  const float* points2 = (const float*)d_in[3];
  const float* fc1_w   = (const float*)d_in[4];
  const float* fc1_b   = (const float*)d_in[5];
  const float* bn1_g   = (const float*)d_in[6];
  const float* bn1_b   = (const float*)d_in[7];
  const float* fc2_w   = (const float*)d_in[8];
  const float* fc2_b   = (const float*)d_in[9];
  const float* bn2_g   = (const float*)d_in[10];
  const float* bn2_b   = (const float*)d_in[11];

  // workspace (~17.5 MB): Y1 bf16 + bf16 weight transposes + stats/coef
  char* ws = (char*)d_ws;
  u16*   Y1    = (u16*)(ws);                       // 16384*512*2 = 16,777,216 B
  u16*   wT1   = (u16*)(ws + 16777216);            // 512*1024*2 = 1,048,576 B
  u16*   wT2   = (u16*)(ws + 17825792);            // 512*512*2  =   524,288 B
  float* stats = (float*)(ws + 18350080);          // 2048 f32
  float* coef  = (float*)(ws + 18358272);          // 2048 f32

  float* out  = (float*)d_out;
  float* outF = out + 196608;   // feats region [65536][512] f32; holds pre-BN Y2 mid-flight

  zero_stats<<<8, 256, 0, stream>>>(stats);
  transpose_w<<<(1024*512 + 255)/256, 256, 0, stream>>>(fc1_w, wT1, 1024, 512);
  transpose_w<<<( 512*512 + 255)/256, 256, 0, stream>>>(fc2_w, wT2,  512, 512);

  // 1D swizzled grids: grid = MT*4, MT multiple of 8 (128 and 512 both ok)
  gemm_mfma<<<512, 256, 0, stream>>>(points1, wT1, fc1_b, Y1,   M1, 1024, 0,
                                     stats,        stats + 512);
  gemm_mfma<<<2048, 256, 0, stream>>>(points2, wT2, fc2_b, outF, M2,  512, 1,
                                      stats + 1024, stats + 1536);

  bn_coeff<<<1, 512, 0, stream>>>(stats, bn1_g, bn1_b, bn2_g, bn2_b, coef);

  copy_xyz<<<192, 256, 0, stream>>>((const uint4*)xyz2, (uint4*)out);
  interp_final<<<65536, 64, 0, stream>>>(xyz1, xyz2, Y1, coef, outF);
}

// Round 3
// 465.002 us; speedup vs baseline: 1.2977x; 1.0296x over previous
//
#include <hip/hip_runtime.h>
#include <stdint.h>

typedef unsigned short u16;
typedef __attribute__((ext_vector_type(8))) short short8;
typedef __attribute__((ext_vector_type(4))) float floatx4;

#define BB 16
#define NN1 1024
#define NN2 4096
#define DIM 512
#define M1 (BB*NN1)    // 16384
#define M2 (BB*NN2)    // 65536

__device__ __forceinline__ float bf2f(u16 u){
  union { unsigned int i; float f; } v; v.i = ((unsigned int)u) << 16; return v.f;
}
__device__ __forceinline__ u16 f2bf(float f){
  union { float f; unsigned int i; } v; v.f = f;
  unsigned int i = v.i;
  return (u16)((i + 0x7FFFu + ((i >> 16) & 1u)) >> 16);  // RNE (exact for bf16-quantized)
}

// packed f32x2 -> bf16x2 (RNE, single VALU instr)
__device__ __forceinline__ uint32_t cvtpk(float lo, float hi){
  uint32_t r;
  asm("v_cvt_pk_bf16_f32 %0, %1, %2" : "=v"(r) : "v"(lo), "v"(hi));
  return r;
}

// async global->LDS, 16B per lane; LDS dest = wave-uniform base + lane*16
__device__ __forceinline__ void gload_lds16(const void* g, void* l){
  __builtin_amdgcn_global_load_lds(
      (const __attribute__((address_space(1))) void*)g,
      (__attribute__((address_space(3))) void*)l, 16, 0, 0);
}

// ---- prep: zero stats + both weight transposes (f32 [K][N] -> bf16 [N][K]) ----
__global__ void prep(const float* __restrict__ fc1_w, const float* __restrict__ fc2_w,
                     u16* __restrict__ wT1, u16* __restrict__ wT2,
                     float* __restrict__ stats){
  int idx = blockIdx.x * 256 + threadIdx.x;   // grid 3072 -> 786432
  if (idx < 2048) stats[idx] = 0.0f;
  if (idx < 512 * 1024){
    int n = idx >> 10, k = idx & 1023;        // wT1[n][k] = fc1_w[k][n]
    wT1[idx] = f2bf(fc1_w[k * 512 + n]);
  } else {
    int j = idx - 512 * 1024;
    int n = j >> 9, k = j & 511;              // wT2[n][k] = fc2_w[k][n]
    wT2[j] = f2bf(fc2_w[k * 512 + n]);
  }
}

// ---- MFMA GEMM: Y[M][512] = A_f32[M][K] @ W; BT = bf16 W^T [512][K] ----
// 1D grid, XCD-aware swizzle. A: f32 load -> cvt_pk -> swizzled ds_write.
// B: global_load_lds dwordx4 with PRE-SWIZZLED per-lane source (linear LDS dest).
// Fused per-column sum/sumsq (BN stats) via block reduction + atomics.
__global__ __launch_bounds__(256) void gemm_mfma(
    const float* __restrict__ A, const u16* __restrict__ BT,
    const float* __restrict__ bias, void* __restrict__ Yv,
    int M, int K, int out_is_f32,
    float* __restrict__ sum, float* __restrict__ sumsq)
{
  const int N = 512;
  // unpadded [128][32] bf16, chunk pos = kc ^ ((row>>1)&3): conflict-free b128 r/w
  __shared__ u16 As[128 * 32];
  __shared__ u16 Bs[128 * 32];
  int tid  = threadIdx.x;
  int lane = tid & 63, wave = tid >> 6;

  // swizzle decode: id%8 == bm%8 -> same-panel blocks share an XCD L2
  int id = blockIdx.x;
  int bm = (id & 7) + ((id >> 5) << 3);
  int bn = (id >> 3) & 3;

  int wm = (wave & 1) * 64, wn = (wave >> 1) * 64;
  int r16 = lane & 15, quad = lane >> 4;

  floatx4 acc[4][4];
  for (int i = 0; i < 4; i++)
    for (int j = 0; j < 4; j++)
      acc[i][j] = (floatx4)(0.0f);

  int lr = tid >> 2;            // 0..63  (A staging row)
  int kc = tid & 3;             // k-chunk 0..3 (8 consecutive k per thread)

  const float* Ag = A  + (size_t)(bm * 128) * K;
  const u16*   Bg = BT + (size_t)(bn * 128) * K;

  // B source pre-swizzle: LDS chunk p = wave*128 + t*64 + lane (linear dest),
  // p -> row = p>>2, pos = p&3, source k-chunk = pos ^ ((row>>1)&3)
  int pb0 = wave * 128 + lane;
  int rb0 = pb0 >> 2, cb0 = (pb0 & 3) ^ ((rb0 >> 1) & 3);
  int pb1 = pb0 + 64;
  int rb1 = pb1 >> 2, cb1 = (pb1 & 3) ^ ((rb1 >> 1) & 3);
  const u16* bsrc0 = Bg + (size_t)rb0 * K + cb0 * 8;
  const u16* bsrc1 = Bg + (size_t)rb1 * K + cb1 * 8;
  u16* bdst0 = &Bs[(wave * 128) * 8];        // wave-uniform
  u16* bdst1 = &Bs[(wave * 128 + 64) * 8];

  int rsw = ((r16 >> 1) & 3) ^ quad;   // read chunk position (XOR un-swizzle)

  for (int k0 = 0; k0 < K; k0 += 32){
    gload_lds16(bsrc0 + k0, bdst0);
    gload_lds16(bsrc1 + k0, bdst1);
    for (int rr = 0; rr < 2; rr++){
      int row = lr + rr * 64;
      const float* ap = Ag + (size_t)row * K + k0 + kc * 8;
      float4 a0 = *(const float4*)ap;
      float4 a1 = *(const float4*)(ap + 4);
      uint4 tv;
      tv.x = cvtpk(a0.x, a0.y);
      tv.y = cvtpk(a0.z, a0.w);
      tv.z = cvtpk(a1.x, a1.y);
      tv.w = cvtpk(a1.z, a1.w);
      int dst = row * 32 + ((kc ^ ((row >> 1) & 3)) * 8);
      *(uint4*)(&As[dst]) = tv;
    }
    __syncthreads();
    short8 af[4], bfr[4];
    for (int i = 0; i < 4; i++) af[i]  = *(const short8*)(&As[(wm + i*16 + r16) * 32 + rsw * 8]);
    for (int j = 0; j < 4; j++) bfr[j] = *(const short8*)(&Bs[(wn + j*16 + r16) * 32 + rsw * 8]);
    for (int i = 0; i < 4; i++)
      for (int j = 0; j < 4; j++)
        acc[i][j] = __builtin_amdgcn_mfma_f32_16x16x32_bf16(af[i], bfr[j], acc[i][j], 0, 0, 0);
    __syncthreads();
  }

  // epilogue: C/D layout col = lane&15, row = quad*4 + reg (m89-verified)
  float cs[4] = {0.f, 0.f, 0.f, 0.f};
  float cq[4] = {0.f, 0.f, 0.f, 0.f};
  for (int i = 0; i < 4; i++){
    int rowb = bm * 128 + wm + i * 16 + quad * 4;
    for (int j = 0; j < 4; j++){
      int col = bn * 128 + wn + j * 16 + r16;
      float bv = bias[col];
      for (int r = 0; r < 4; r++){
        float v = acc[i][j][r] + bv;
        cs[j] += v; cq[j] += v * v;
        size_t idx = (size_t)(rowb + r) * N + col;
        if (out_is_f32) ((float*)Yv)[idx] = v;
        else            ((u16*)Yv)[idx]   = f2bf(v);
      }
    }
  }

  // column-stat reduction: quads within wave (shfl), wm-halves via LDS, 1 atomic each
  for (int j = 0; j < 4; j++){
    cs[j] += __shfl_xor(cs[j], 16); cs[j] += __shfl_xor(cs[j], 32);
    cq[j] += __shfl_xor(cq[j], 16); cq[j] += __shfl_xor(cq[j], 32);
  }
  float* S = (float*)As;   // reuse: [wmh][stat][128 cols] = 512 f32
  if (lane < 16){
    int wmh = wave & 1, wnh = wave >> 1;
    for (int j = 0; j < 4; j++){
      int c = wnh * 64 + j * 16 + r16;
      S[wmh * 256 + c]       = cs[j];
      S[wmh * 256 + 128 + c] = cq[j];
    }
  }
  __syncthreads();
  {
    int stat = tid >> 7, c = tid & 127;
    float v = S[stat * 128 + c] + S[256 + stat * 128 + c];
    float* dstp = stat ? sumsq : sum;
    atomicAdd(&dstp[bn * 128 + c], v);
  }
}

// ---- BN coefficients (block 0) + xyz2 passthrough copy (blocks 1..96) ----
__global__ void bn_coeff_copy(const float* __restrict__ stats,
                              const float* __restrict__ g1, const float* __restrict__ be1,
                              const float* __restrict__ g2, const float* __restrict__ be2,
                              float* __restrict__ coef,
                              const uint4* __restrict__ xsrc, uint4* __restrict__ xdst){
  int b = blockIdx.x, tid = threadIdx.x;
  if (b == 0){
    int c = tid;  // 512
    {
      float mu  = stats[c] / (float)M1;
      float var = stats[512 + c] / (float)M1 - mu * mu;
      var = fmaxf(var, 0.0f);
      float a = g1[c] * (1.0f / sqrtf(var + 1e-5f));
      coef[c] = a;
      coef[512 + c] = be1[c] - mu * a;
    }
    {
      float mu  = stats[1024 + c] / (float)M2;
      float var = stats[1536 + c] / (float)M2 - mu * mu;
      var = fmaxf(var, 0.0f);
      float a = g2[c] * (1.0f / sqrtf(var + 1e-5f));
      coef[1024 + c] = a;
      coef[1536 + c] = be2[c] - mu * a;
    }
  } else {
    int i = (b - 1) * 512 + tid;   // 96 * 512 = 49152 uint4 = 786432 B
    xdst[i] = xsrc[i];
  }
}

// ---- 3-NN inverse-distance interp FUSED with BN1/BN2+ReLU+add; one wave/query ----
// outF row holds pre-BN Y2 (f32) on entry; on exit it holds the final feats row.
__global__ __launch_bounds__(64) void interp_final(
    const float* __restrict__ xyz1, const float* __restrict__ xyz2,
    const u16* __restrict__ Y1, const float* __restrict__ coef,
    float* __restrict__ outF)
{
  int lane = threadIdx.x;
  int bid  = blockIdx.x;
  int b = bid >> 12;           // /4096

  const float* pd = xyz2 + (size_t)bid * 3;
  double xd = (double)pd[0];
  double yd = (double)pd[1];
  double zd = (double)pd[2];

  // f64 distances (exact for bf16-quantized coords -> true ordering)
  double dl[16];
  const float* ps = xyz1 + (size_t)b * NN1 * 3;
  for (int s = 0; s < 16; s++){
    const float* q = ps + (s * 64 + lane) * 3;
    double dx = xd - (double)q[0];
    double dy = yd - (double)q[1];
    double dz = zd - (double)q[2];
    dl[s] = dx * dx + dy * dy + dz * dz;
  }

  double dsel[3]; int isel[3];
  for (int p = 0; p < 3; p++){
    double dm = dl[0]; int sm = 0;
    for (int s = 1; s < 16; s++) if (dl[s] < dm){ dm = dl[s]; sm = s; }
    int im = sm * 64 + lane;
    for (int off = 1; off < 64; off <<= 1){
      double od = __shfl_xor(dm, off);
      int    oi = __shfl_xor(im, off);
      if (od < dm || (od == dm && oi < im)){ dm = od; im = oi; }  // stable: lowest index
    }
    dsel[p] = dm; isel[p] = im;
    if ((im & 63) == lane) dl[im >> 6] = 1e300;  // owner invalidates winner
  }

  double w0 = 1.0 / (dsel[0] + 1e-8);
  double w1 = 1.0 / (dsel[1] + 1e-8);
  double w2 = 1.0 / (dsel[2] + 1e-8);
  double wsum = w0 + w1 + w2;
  float f0 = (float)(w0 / wsum), f1 = (float)(w1 / wsum), f2 = (float)(w2 / wsum);

  const u16* r0 = Y1 + (size_t)(b * NN1 + isel[0]) * DIM;
  const u16* r1 = Y1 + (size_t)(b * NN1 + isel[1]) * DIM;
  const u16* r2 = Y1 + (size_t)(b * NN1 + isel[2]) * DIM;
  float* o = outF + (size_t)bid * DIM;

  int c0 = lane * 8;  // 8 contiguous channels per lane
  uint4 q0 = *(const uint4*)(r0 + c0);
  uint4 q1 = *(const uint4*)(r1 + c0);
  uint4 q2 = *(const uint4*)(r2 + c0);
  float4 ylo = *(const float4*)(o + c0);
  float4 yhi = *(const float4*)(o + c0 + 4);
  const u16* p0 = (const u16*)&q0;
  const u16* p1 = (const u16*)&q1;
  const u16* p2 = (const u16*)&q2;
  float yv[8] = { ylo.x, ylo.y, ylo.z, ylo.w, yhi.x, yhi.y, yhi.z, yhi.w };
  float res[8];
  for (int j = 0; j < 8; j++){
    int c = c0 + j;
    float a1 = coef[c],        b1 = coef[512 + c];
    float a2 = coef[1024 + c], b2 = coef[1536 + c];
    float v0 = fmaxf(a1 * bf2f(p0[j]) + b1, 0.0f);
    float v1 = fmaxf(a1 * bf2f(p1[j]) + b1, 0.0f);
    float v2 = fmaxf(a1 * bf2f(p2[j]) + b1, 0.0f);
    float vi = f0 * v0 + f1 * v1 + f2 * v2;
    float y2 = fmaxf(a2 * yv[j] + b2, 0.0f);
    res[j] = vi + y2;
  }
  *(float4*)(o + c0)     = make_float4(res[0], res[1], res[2], res[3]);
  *(float4*)(o + c0 + 4) = make_float4(res[4], res[5], res[6], res[7]);
}

extern "C" void kernel_launch(void* const* d_in, const int* in_sizes, int n_in,
                              void* d_out, int out_size, void* d_ws, size_t ws_size,
                              hipStream_t stream){
  const float* xyz1    = (const float*)d_in[0];
  const float* points1 = (const float*)d_in[1];
  const float* xyz2    = (const float*)d_in[2];
  const float* points2 = (const float*)d_in[3];
  const float* fc1_w   = (const float*)d_in[4];
  const float* fc1_b   = (const float*)d_in[5];
  const float* bn1_g   = (const float*)d_in[6];
  const float* bn1_b   = (const float*)d_in[7];
  const float* fc2_w   = (const float*)d_in[8];
  const float* fc2_b   = (const float*)d_in[9];
  const float* bn2_g   = (const float*)d_in[10];
  const float* bn2_b   = (const float*)d_in[11];

  // workspace (~17.5 MB): Y1 bf16 + bf16 weight transposes + stats/coef
  char* ws = (char*)d_ws;
  u16*   Y1    = (u16*)(ws);                       // 16384*512*2 = 16,777,216 B
  u16*   wT1   = (u16*)(ws + 16777216);            // 512*1024*2 = 1,048,576 B
  u16*   wT2   = (u16*)(ws + 17825792);            // 512*512*2  =   524,288 B
  float* stats = (float*)(ws + 18350080);          // 2048 f32
  float* coef  = (float*)(ws + 18358272);          // 2048 f32

  float* out  = (float*)d_out;
  float* outF = out + 196608;   // feats region [65536][512] f32; holds pre-BN Y2 mid-flight

  prep<<<3072, 256, 0, stream>>>(fc1_w, fc2_w, wT1, wT2, stats);

  // 1D swizzled grids: grid = MT*4, MT multiple of 8 (128 and 512 both ok)
  gemm_mfma<<<512, 256, 0, stream>>>(points1, wT1, fc1_b, Y1,   M1, 1024, 0,
                                     stats,        stats + 512);
  gemm_mfma<<<2048, 256, 0, stream>>>(points2, wT2, fc2_b, outF, M2,  512, 1,
                                      stats + 1024, stats + 1536);

  bn_coeff_copy<<<97, 512, 0, stream>>>(stats, bn1_g, bn1_b, bn2_g, bn2_b, coef,
                                        (const uint4*)xyz2, (uint4*)out);

  interp_final<<<65536, 64, 0, stream>>>(xyz1, xyz2, Y1, coef, outF);
}

// Round 4
// 462.052 us; speedup vs baseline: 1.3060x; 1.0064x over previous
//
#include <hip/hip_runtime.h>
#include <stdint.h>

typedef unsigned short u16;
typedef __attribute__((ext_vector_type(8))) short short8;
typedef __attribute__((ext_vector_type(4))) float floatx4;

#define BB 16
#define NN1 1024
#define NN2 4096
#define DIM 512
#define M1 (BB*NN1)    // 16384
#define M2 (BB*NN2)    // 65536

__device__ __forceinline__ float bf2f(u16 u){
  union { unsigned int i; float f; } v; v.i = ((unsigned int)u) << 16; return v.f;
}
__device__ __forceinline__ u16 f2bf(float f){
  union { float f; unsigned int i; } v; v.f = f;
  unsigned int i = v.i;
  return (u16)((i + 0x7FFFu + ((i >> 16) & 1u)) >> 16);  // RNE (exact for bf16-quantized)
}

// packed f32x2 -> bf16x2 (RNE, single VALU instr)
__device__ __forceinline__ uint32_t cvtpk(float lo, float hi){
  uint32_t r;
  asm("v_cvt_pk_bf16_f32 %0, %1, %2" : "=v"(r) : "v"(lo), "v"(hi));
  return r;
}

// fast f32 reciprocal (1 ulp) — weights only, not orderings
__device__ __forceinline__ float rcpf(float x){
  float r; asm("v_rcp_f32 %0, %1" : "=v"(r) : "v"(x)); return r;
}

// async global->LDS, 16B per lane; LDS dest = wave-uniform base + lane*16
__device__ __forceinline__ void gload_lds16(const void* g, void* l){
  __builtin_amdgcn_global_load_lds(
      (const __attribute__((address_space(1))) void*)g,
      (__attribute__((address_space(3))) void*)l, 16, 0, 0);
}

// ---- prep: zero stats + both weight transposes (f32 [K][N] -> bf16 [N][K]) ----
__global__ void prep(const float* __restrict__ fc1_w, const float* __restrict__ fc2_w,
                     u16* __restrict__ wT1, u16* __restrict__ wT2,
                     float* __restrict__ stats){
  int idx = blockIdx.x * 256 + threadIdx.x;   // grid 3072 -> 786432
  if (idx < 2048) stats[idx] = 0.0f;
  if (idx < 512 * 1024){
    int n = idx >> 10, k = idx & 1023;        // wT1[n][k] = fc1_w[k][n]
    wT1[idx] = f2bf(fc1_w[k * 512 + n]);
  } else {
    int j = idx - 512 * 1024;
    int n = j >> 9, k = j & 511;              // wT2[n][k] = fc2_w[k][n]
    wT2[j] = f2bf(fc2_w[k * 512 + n]);
  }
}

// ---- MFMA GEMM: Y[M][512] = A_f32[M][K] @ W; BT = bf16 W^T [512][K] ----
// 2-PHASE double-buffered pipeline (T3 minimum recipe): issue STAGE(k+1)
// (A global->reg, B global_load_lds) BEFORE MFMA(k); cvt+ds_write A(k+1)
// after MFMA; ONE barrier per K-step. Hides load latency under compute.
__global__ __launch_bounds__(256) void gemm_mfma(
    const float* __restrict__ A, const u16* __restrict__ BT,
    const float* __restrict__ bias, void* __restrict__ Yv,
    int M, int K, int out_is_f32,
    float* __restrict__ sum, float* __restrict__ sumsq)
{
  const int N = 512;
  // unpadded [128][32] bf16 per buffer, chunk pos = kc ^ ((row>>1)&3)
  __shared__ u16 As[2][128 * 32];
  __shared__ u16 Bs[2][128 * 32];
  int tid  = threadIdx.x;
  int lane = tid & 63, wave = tid >> 6;

  // swizzle decode: id%8 == bm%8 -> same-panel blocks share an XCD L2
  int id = blockIdx.x;
  int bm = (id & 7) + ((id >> 5) << 3);
  int bn = (id >> 3) & 3;

  int wm = (wave & 1) * 64, wn = (wave >> 1) * 64;
  int r16 = lane & 15, quad = lane >> 4;

  floatx4 acc[4][4];
#pragma unroll
  for (int i = 0; i < 4; i++)
#pragma unroll
    for (int j = 0; j < 4; j++)
      acc[i][j] = (floatx4)(0.0f);

  int lr = tid >> 2;            // 0..63  (A staging row)
  int kc = tid & 3;             // k-chunk 0..3 (8 consecutive k per thread)

  const float* Ag = A  + (size_t)(bm * 128) * K;
  const u16*   Bg = BT + (size_t)(bn * 128) * K;

  // A staging: rows lr, lr+64; swizzled LDS dest (note: adst1 = adst0 + 2048)
  const float* ap0 = Ag + (size_t)lr * K + kc * 8;
  const float* ap1 = Ag + (size_t)(lr + 64) * K + kc * 8;
  int adst0 = lr * 32 + ((kc ^ ((lr >> 1) & 3)) * 8);
  int adst1 = adst0 + 64 * 32;

  // B source pre-swizzle: LDS chunk p = wave*128 + t*64 + lane (linear dest),
  // p -> row = p>>2, pos = p&3, source k-chunk = pos ^ ((row>>1)&3)
  int pb0 = wave * 128 + lane;
  int rb0 = pb0 >> 2, cb0 = (pb0 & 3) ^ ((rb0 >> 1) & 3);
  int pb1 = pb0 + 64;
  int rb1 = pb1 >> 2, cb1 = (pb1 & 3) ^ ((rb1 >> 1) & 3);
  const u16* bsrc0 = Bg + (size_t)rb0 * K + cb0 * 8;
  const u16* bsrc1 = Bg + (size_t)rb1 * K + cb1 * 8;
  int boff = (wave * 128) * 8;   // wave-uniform elem offset within a buffer

  int rsw = ((r16 >> 1) & 3) ^ quad;   // read chunk position (XOR un-swizzle)

  int NS = K >> 5;
  float4 a00, a01, a10, a11;

  // prologue: stage tile 0 into buffer 0
  a00 = *(const float4*)(ap0);     a01 = *(const float4*)(ap0 + 4);
  a10 = *(const float4*)(ap1);     a11 = *(const float4*)(ap1 + 4);
  gload_lds16(bsrc0, &Bs[0][boff]);
  gload_lds16(bsrc1, &Bs[0][boff + 512]);
  {
    uint4 tv0, tv1;
    tv0.x = cvtpk(a00.x, a00.y); tv0.y = cvtpk(a00.z, a00.w);
    tv0.z = cvtpk(a01.x, a01.y); tv0.w = cvtpk(a01.z, a01.w);
    tv1.x = cvtpk(a10.x, a10.y); tv1.y = cvtpk(a10.z, a10.w);
    tv1.z = cvtpk(a11.x, a11.y); tv1.w = cvtpk(a11.z, a11.w);
    *(uint4*)(&As[0][adst0]) = tv0;
    *(uint4*)(&As[0][adst1]) = tv1;
  }
  __syncthreads();

  int cur = 0;
  for (int ks = 0; ks < NS; ks++){
    int k1 = (ks + 1) << 5;
    if (ks + 1 < NS){
      // STAGE(k+1): issue loads early — latency hides under MFMA(k)
      a00 = *(const float4*)(ap0 + k1); a01 = *(const float4*)(ap0 + k1 + 4);
      a10 = *(const float4*)(ap1 + k1); a11 = *(const float4*)(ap1 + k1 + 4);
      gload_lds16(bsrc0 + k1, &Bs[cur ^ 1][boff]);
      gload_lds16(bsrc1 + k1, &Bs[cur ^ 1][boff + 512]);
    }
    short8 af[4], bfr[4];
#pragma unroll
    for (int i = 0; i < 4; i++) af[i]  = *(const short8*)(&As[cur][(wm + i*16 + r16) * 32 + rsw * 8]);
#pragma unroll
    for (int j = 0; j < 4; j++) bfr[j] = *(const short8*)(&Bs[cur][(wn + j*16 + r16) * 32 + rsw * 8]);
#pragma unroll
    for (int i = 0; i < 4; i++)
#pragma unroll
      for (int j = 0; j < 4; j++)
        acc[i][j] = __builtin_amdgcn_mfma_f32_16x16x32_bf16(af[i], bfr[j], acc[i][j], 0, 0, 0);
    if (ks + 1 < NS){
      uint4 tv0, tv1;   // compiler waits vmcnt for a* here (B glds stay in flight)
      tv0.x = cvtpk(a00.x, a00.y); tv0.y = cvtpk(a00.z, a00.w);
      tv0.z = cvtpk(a01.x, a01.y); tv0.w = cvtpk(a01.z, a01.w);
      tv1.x = cvtpk(a10.x, a10.y); tv1.y = cvtpk(a10.z, a10.w);
      tv1.z = cvtpk(a11.x, a11.y); tv1.w = cvtpk(a11.z, a11.w);
      *(uint4*)(&As[cur ^ 1][adst0]) = tv0;
      *(uint4*)(&As[cur ^ 1][adst1]) = tv1;
    }
    __syncthreads();   // one barrier per K-step
    cur ^= 1;
  }

  // epilogue: C/D layout col = lane&15, row = quad*4 + reg (m89-verified)
  float cs[4] = {0.f, 0.f, 0.f, 0.f};
  float cq[4] = {0.f, 0.f, 0.f, 0.f};
#pragma unroll
  for (int i = 0; i < 4; i++){
    int rowb = bm * 128 + wm + i * 16 + quad * 4;
#pragma unroll
    for (int j = 0; j < 4; j++){
      int col = bn * 128 + wn + j * 16 + r16;
      float bv = bias[col];
#pragma unroll
      for (int r = 0; r < 4; r++){
        float v = acc[i][j][r] + bv;
        cs[j] += v; cq[j] += v * v;
        size_t idx = (size_t)(rowb + r) * N + col;
        if (out_is_f32) ((float*)Yv)[idx] = v;
        else            ((u16*)Yv)[idx]   = f2bf(v);
      }
    }
  }

  // column-stat reduction: quads within wave (shfl), wm-halves via LDS, 1 atomic each
#pragma unroll
  for (int j = 0; j < 4; j++){
    cs[j] += __shfl_xor(cs[j], 16); cs[j] += __shfl_xor(cs[j], 32);
    cq[j] += __shfl_xor(cq[j], 16); cq[j] += __shfl_xor(cq[j], 32);
  }
  float* S = (float*)As;   // reuse buffer 0: [wmh][stat][128 cols] = 512 f32
  if (lane < 16){
    int wmh = wave & 1, wnh = wave >> 1;
#pragma unroll
    for (int j = 0; j < 4; j++){
      int c = wnh * 64 + j * 16 + r16;
      S[wmh * 256 + c]       = cs[j];
      S[wmh * 256 + 128 + c] = cq[j];
    }
  }
  __syncthreads();
  {
    int stat = tid >> 7, c = tid & 127;
    float v = S[stat * 128 + c] + S[256 + stat * 128 + c];
    float* dstp = stat ? sumsq : sum;
    atomicAdd(&dstp[bn * 128 + c], v);
  }
}

// ---- BN coefficients (block 0) + xyz2 passthrough copy (blocks 1..96) ----
__global__ void bn_coeff_copy(const float* __restrict__ stats,
                              const float* __restrict__ g1, const float* __restrict__ be1,
                              const float* __restrict__ g2, const float* __restrict__ be2,
                              float* __restrict__ coef,
                              const uint4* __restrict__ xsrc, uint4* __restrict__ xdst){
  int b = blockIdx.x, tid = threadIdx.x;
  if (b == 0){
    int c = tid;  // 512
    {
      float mu  = stats[c] / (float)M1;
      float var = stats[512 + c] / (float)M1 - mu * mu;
      var = fmaxf(var, 0.0f);
      float a = g1[c] * (1.0f / sqrtf(var + 1e-5f));
      coef[c] = a;
      coef[512 + c] = be1[c] - mu * a;
    }
    {
      float mu  = stats[1024 + c] / (float)M2;
      float var = stats[1536 + c] / (float)M2 - mu * mu;
      var = fmaxf(var, 0.0f);
      float a = g2[c] * (1.0f / sqrtf(var + 1e-5f));
      coef[1024 + c] = a;
      coef[1536 + c] = be2[c] - mu * a;
    }
  } else {
    int i = (b - 1) * 512 + tid;   // 96 * 512 = 49152 uint4 = 786432 B
    xdst[i] = xsrc[i];
  }
}

// ---- 3-NN inverse-distance interp FUSED with BN1/BN2+ReLU+add; one wave/query ----
// u64 sort keys: positive-double bits are order-isomorphic to u64; low 10
// mantissa bits hold the point index -> stable lowest-index tie-break for
// exact ties, ordering unchanged for relative gaps > 2^-44 (semantics of
// the previously-passing f64+(d,idx) compare preserved). Distances still
// computed in f64 (exact ordering for quantized coords). Weights in f32.
__global__ __launch_bounds__(64) void interp_final(
    const float* __restrict__ xyz1, const float* __restrict__ xyz2,
    const u16* __restrict__ Y1, const float* __restrict__ coef,
    float* __restrict__ outF)
{
  int lane = threadIdx.x;
  int bid  = blockIdx.x;
  int b = bid >> 12;           // /4096

  const float* pd = xyz2 + (size_t)bid * 3;
  double xd = (double)pd[0];
  double yd = (double)pd[1];
  double zd = (double)pd[2];

  unsigned long long kl[16];
  const float* ps = xyz1 + (size_t)b * NN1 * 3;
#pragma unroll
  for (int s = 0; s < 16; s++){
    const float* q = ps + (s * 64 + lane) * 3;
    double dx = xd - (double)q[0];
    double dy = yd - (double)q[1];
    double dz = zd - (double)q[2];
    double d = dx * dx + dy * dy + dz * dz;
    unsigned long long bits = (unsigned long long)__double_as_longlong(d);
    kl[s] = (bits & ~1023ULL) | (unsigned long long)(s * 64 + lane);
  }

  unsigned long long selk[3];
  for (int p = 0; p < 3; p++){
    unsigned long long m = kl[0];
#pragma unroll
    for (int s = 1; s < 16; s++) if (kl[s] < m) m = kl[s];
    for (int off = 1; off < 64; off <<= 1){
      unsigned long long o = (unsigned long long)__shfl_xor((long long)m, off);
      if (o < m) m = o;
    }
    selk[p] = m;
    if (p < 2){
      // unique keys (index embedded): exactly one (s,lane) matches
#pragma unroll
      for (int s = 0; s < 16; s++) if (kl[s] == m) kl[s] = ~0ULL;
    }
  }

  int i0 = (int)(selk[0] & 1023ULL);
  int i1 = (int)(selk[1] & 1023ULL);
  int i2 = (int)(selk[2] & 1023ULL);
  float d0 = (float)__longlong_as_double((long long)(selk[0] & ~1023ULL));
  float d1 = (float)__longlong_as_double((long long)(selk[1] & ~1023ULL));
  float d2 = (float)__longlong_as_double((long long)(selk[2] & ~1023ULL));
  float w0 = rcpf(d0 + 1e-8f);
  float w1 = rcpf(d1 + 1e-8f);
  float w2 = rcpf(d2 + 1e-8f);
  float inv = rcpf(w0 + w1 + w2);
  float f0 = w0 * inv, f1 = w1 * inv, f2 = w2 * inv;

  const u16* r0 = Y1 + (size_t)(b * NN1 + i0) * DIM;
  const u16* r1 = Y1 + (size_t)(b * NN1 + i1) * DIM;
  const u16* r2 = Y1 + (size_t)(b * NN1 + i2) * DIM;
  float* o = outF + (size_t)bid * DIM;

  int c0 = lane * 8;  // 8 contiguous channels per lane
  uint4 q0 = *(const uint4*)(r0 + c0);
  uint4 q1 = *(const uint4*)(r1 + c0);
  uint4 q2 = *(const uint4*)(r2 + c0);
  float4 ylo = *(const float4*)(o + c0);
  float4 yhi = *(const float4*)(o + c0 + 4);
  // vectorized coef loads (4 x 2 float4)
  union { float4 v[2]; float f[8]; } A1u, B1u, A2u, B2u;
  A1u.v[0] = *(const float4*)(coef + c0);        A1u.v[1] = *(const float4*)(coef + c0 + 4);
  B1u.v[0] = *(const float4*)(coef + 512 + c0);  B1u.v[1] = *(const float4*)(coef + 512 + c0 + 4);
  A2u.v[0] = *(const float4*)(coef + 1024 + c0); A2u.v[1] = *(const float4*)(coef + 1024 + c0 + 4);
  B2u.v[0] = *(const float4*)(coef + 1536 + c0); B2u.v[1] = *(const float4*)(coef + 1536 + c0 + 4);
  const u16* p0 = (const u16*)&q0;
  const u16* p1 = (const u16*)&q1;
  const u16* p2 = (const u16*)&q2;
  float yv[8] = { ylo.x, ylo.y, ylo.z, ylo.w, yhi.x, yhi.y, yhi.z, yhi.w };
  float res[8];
#pragma unroll
  for (int j = 0; j < 8; j++){
    float a1 = A1u.f[j], b1 = B1u.f[j];
    float a2 = A2u.f[j], b2 = B2u.f[j];
    float v0 = fmaxf(a1 * bf2f(p0[j]) + b1, 0.0f);
    float v1 = fmaxf(a1 * bf2f(p1[j]) + b1, 0.0f);
    float v2 = fmaxf(a1 * bf2f(p2[j]) + b1, 0.0f);
    float vi = f0 * v0 + f1 * v1 + f2 * v2;
    float y2 = fmaxf(a2 * yv[j] + b2, 0.0f);
    res[j] = vi + y2;
  }
  *(float4*)(o + c0)     = make_float4(res[0], res[1], res[2], res[3]);
  *(float4*)(o + c0 + 4) = make_float4(res[4], res[5], res[6], res[7]);
}

extern "C" void kernel_launch(void* const* d_in, const int* in_sizes, int n_in,
                              void* d_out, int out_size, void* d_ws, size_t ws_size,
                              hipStream_t stream){
  const float* xyz1    = (const float*)d_in[0];
  const float* points1 = (const float*)d_in[1];
  const float* xyz2    = (const float*)d_in[2];
  const float* points2 = (const float*)d_in[3];
  const float* fc1_w   = (const float*)d_in[4];
  const float* fc1_b   = (const float*)d_in[5];
  const float* bn1_g   = (const float*)d_in[6];
  const float* bn1_b   = (const float*)d_in[7];
  const float* fc2_w   = (const float*)d_in[8];
  const float* fc2_b   = (const float*)d_in[9];
  const float* bn2_g   = (const float*)d_in[10];
  const float* bn2_b   = (const float*)d_in[11];

  // workspace (~17.5 MB): Y1 bf16 + bf16 weight transposes + stats/coef
  char* ws = (char*)d_ws;
  u16*   Y1    = (u16*)(ws);                       // 16384*512*2 = 16,777,216 B
  u16*   wT1   = (u16*)(ws + 16777216);            // 512*1024*2 = 1,048,576 B
  u16*   wT2   = (u16*)(ws + 17825792);            // 512*512*2  =   524,288 B
  float* stats = (float*)(ws + 18350080);          // 2048 f32
  float* coef  = (float*)(ws + 18358272);          // 2048 f32

  float* out  = (float*)d_out;
  float* outF = out + 196608;   // feats region [65536][512] f32; holds pre-BN Y2 mid-flight

  prep<<<3072, 256, 0, stream>>>(fc1_w, fc2_w, wT1, wT2, stats);

  // 1D swizzled grids: grid = MT*4, MT multiple of 8 (128 and 512 both ok)
  gemm_mfma<<<512, 256, 0, stream>>>(points1, wT1, fc1_b, Y1,   M1, 1024, 0,
                                     stats,        stats + 512);
  gemm_mfma<<<2048, 256, 0, stream>>>(points2, wT2, fc2_b, outF, M2,  512, 1,
                                      stats + 1024, stats + 1536);

  bn_coeff_copy<<<97, 512, 0, stream>>>(stats, bn1_g, bn1_b, bn2_g, bn2_b, coef,
                                        (const uint4*)xyz2, (uint4*)out);

  interp_final<<<65536, 64, 0, stream>>>(xyz1, xyz2, Y1, coef, outF);
}